// Round 8
// baseline (32.949 us; speedup 1.0000x reference)
//
#include <hip/hip_runtime.h>
#include <cstdint>
#include <cmath>

#define EPS_F 1e-8f

constexpr int B = 8, H = 8, CELLS = 8192, W = 256;
constexpr int W4 = 64;                 // float4 per W-row
constexpr int TC = 16;                 // cells per tile
constexpr int NT = 4;                  // tiles per block (double-buffered)
constexpr int NBLK = CELLS / TC;       // 512 tiles per (b,h) row
constexpr int GX = CELLS / (TC * NT);  // 128 blocks per batch row

// ---- DPP rotate-add reduction over a row of 16 lanes (pure VALU) ----------
template <int CTRL>
__device__ __forceinline__ float ror_add(float v) {
    int x = __builtin_amdgcn_update_dpp(0, __builtin_bit_cast(int, v),
                                        CTRL, 0xf, 0xf, false);
    return v + __builtin_bit_cast(float, x);
}
__device__ __forceinline__ float row_sum16(float v) {
    v = ror_add<0x121>(v);   // row_ror:1
    v = ror_add<0x122>(v);   // row_ror:2
    v = ror_add<0x124>(v);   // row_ror:4
    v = ror_add<0x128>(v);   // row_ror:8
    return v;                // every lane holds the 16-lane sum
}

// ---- async global->LDS DMA, 16B per lane ----------------------------------
#define GLOAD_LDS16(g, l)                                                    \
    __builtin_amdgcn_global_load_lds(                                        \
        (__attribute__((address_space(1))) void*)(void*)(g),                 \
        (__attribute__((address_space(3))) void*)(l), 16, 0, 0)

// ---------------------------------------------------------------------------
// Kernel A: fused prep + scores + softmax partials, double-buffered tiles.
// grid = (GX, B) = (128, 8), 256 threads (4 waves).
// lane = hp*16 + wsl (hp 0..3, wsl 0..15); lane covers heads hp and hp+4 on
// W-slots {wsl, wsl+16, wsl+32, wsl+48}; kq/m2 table in 16 f4 VGPRs.
// Per tile: syncthreads (drain DMA) -> issue next-tile DMA -> compute from
// LDS (4 ds_read_b128/cell, DPP reduce) -> raw-barrier epilogue (no vmcnt
// drain, prefetch stays in flight).
// ---------------------------------------------------------------------------
__global__ __launch_bounds__(256, 3) void ca_scores(
    const float4* __restrict__ mem4,    // [B*CELLS][W4]
    const float4* __restrict__ keys4,   // [B*H][W4]
    const float4* __restrict__ mask4,   // [B*H][W4]
    const float* __restrict__ betas,    // [B*H]
    float* __restrict__ out,            // [B*H][CELLS]
    float2* __restrict__ part)          // [B*H][NBLK] (max, sumexp)
{
    __shared__ float4 s_buf[2][TC * W4];   // 2 x 16 KB
    __shared__ float  s_sc[H][TC + 1];     // score transpose buffer

    const int b = blockIdx.y, grp = blockIdx.x, t = threadIdx.x;
    const int lane = t & 63, wv = t >> 6;
    const int hp  = (lane >> 4) & 3;       // head pair id
    const int wsl = lane & 15;             // W-slot within quarter
    const int c0  = grp * (TC * NT);

    // ---- prep loads + per-lane table (L2-hot; FIFO-ahead of DMA) ----
    const float4* __restrict__ kA = keys4 + (size_t)(b * 8 + hp) * W4;
    const float4* __restrict__ mA = mask4 + (size_t)(b * 8 + hp) * W4;
    const float4* __restrict__ kB = keys4 + (size_t)(b * 8 + hp + 4) * W4;
    const float4* __restrict__ mB = mask4 + (size_t)(b * 8 + hp + 4) * W4;
    float4 tb[16];
    float pA = 0.f, pB = 0.f;
#pragma unroll
    for (int j = 0; j < 4; ++j) {
        float4 k = kA[j * 16 + wsl], m = mA[j * 16 + wsl];
        float4 q = make_float4(m.x * m.x, m.y * m.y, m.z * m.z, m.w * m.w);
        tb[j * 4 + 0] = make_float4(k.x * q.x, k.y * q.y, k.z * q.z, k.w * q.w);
        tb[j * 4 + 1] = q;
        float km;
        km = k.x * m.x; pA = fmaf(km, km, pA);
        km = k.y * m.y; pA = fmaf(km, km, pA);
        km = k.z * m.z; pA = fmaf(km, km, pA);
        km = k.w * m.w; pA = fmaf(km, km, pA);
        k = kB[j * 16 + wsl]; m = mB[j * 16 + wsl];
        q = make_float4(m.x * m.x, m.y * m.y, m.z * m.z, m.w * m.w);
        tb[j * 4 + 2] = make_float4(k.x * q.x, k.y * q.y, k.z * q.z, k.w * q.w);
        tb[j * 4 + 3] = q;
        km = k.x * m.x; pB = fmaf(km, km, pB);
        km = k.y * m.y; pB = fmaf(km, km, pB);
        km = k.z * m.z; pB = fmaf(km, km, pB);
        km = k.w * m.w; pB = fmaf(km, km, pB);
    }
    const float beA = betas[b * 8 + hp];
    const float beB = betas[b * 8 + hp + 4];

    // ---- DMA tile 0 into buffer 0 ----
    {
        const float4* __restrict__ g0 = mem4 + ((size_t)b * CELLS + c0) * W4;
#pragma unroll
        for (int i = 0; i < 4; ++i)
            GLOAD_LDS16(g0 + t + i * 256, &s_buf[0][t + i * 256]);
    }
    const float knA = sqrtf(row_sum16(pA));
    const float knB = sqrtf(row_sum16(pB));

#pragma unroll
    for (int nt = 0; nt < NT; ++nt) {
        __syncthreads();                   // drains vmcnt(0): tile nt resident
        const int cur = nt & 1;

        // prefetch next tile into the other buffer (in flight across the
        // raw barriers below; drained by the next loop-top syncthreads)
        if (nt + 1 < NT) {
            const float4* __restrict__ gn =
                mem4 + ((size_t)b * CELLS + c0 + (nt + 1) * TC) * W4;
#pragma unroll
            for (int i = 0; i < 4; ++i)
                GLOAD_LDS16(gn + t + i * 256, &s_buf[cur ^ 1][t + i * 256]);
        }

        // ---- compute 4 cells per wave from s_buf[cur] ----
#pragma unroll
        for (int c = 0; c < 4; ++c) {
            const int cell = wv * 4 + c;
            const float4* __restrict__ pr = &s_buf[cur][cell * W4 + wsl];
            float4 a0 = pr[0], a1 = pr[16], a2 = pr[32], a3 = pr[48];

            float4 dA = make_float4(0.f, 0.f, 0.f, 0.f);
            float4 nA = make_float4(0.f, 0.f, 0.f, 0.f);
            float4 dB = make_float4(0.f, 0.f, 0.f, 0.f);
            float4 nB = make_float4(0.f, 0.f, 0.f, 0.f);

#define ACC(a, j)                                                           \
            {                                                               \
                float4 sq = make_float4(a.x * a.x, a.y * a.y, a.z * a.z, a.w * a.w); \
                float4 kqA = tb[(j) * 4 + 0], qA = tb[(j) * 4 + 1];         \
                float4 kqB = tb[(j) * 4 + 2], qB = tb[(j) * 4 + 3];         \
                dA.x = fmaf(a.x, kqA.x, dA.x); dA.y = fmaf(a.y, kqA.y, dA.y); \
                dA.z = fmaf(a.z, kqA.z, dA.z); dA.w = fmaf(a.w, kqA.w, dA.w); \
                nA.x = fmaf(sq.x, qA.x, nA.x); nA.y = fmaf(sq.y, qA.y, nA.y); \
                nA.z = fmaf(sq.z, qA.z, nA.z); nA.w = fmaf(sq.w, qA.w, nA.w); \
                dB.x = fmaf(a.x, kqB.x, dB.x); dB.y = fmaf(a.y, kqB.y, dB.y); \
                dB.z = fmaf(a.z, kqB.z, dB.z); dB.w = fmaf(a.w, kqB.w, dB.w); \
                nB.x = fmaf(sq.x, qB.x, nB.x); nB.y = fmaf(sq.y, qB.y, nB.y); \
                nB.z = fmaf(sq.z, qB.z, nB.z); nB.w = fmaf(sq.w, qB.w, nB.w); \
            }
            ACC(a0, 0) ACC(a1, 1) ACC(a2, 2) ACC(a3, 3)
#undef ACC

            float d0 = (dA.x + dA.y) + (dA.z + dA.w);
            float n0 = (nA.x + nA.y) + (nA.z + nA.w);
            float d1 = (dB.x + dB.y) + (dB.z + dB.w);
            float n1 = (nB.x + nB.y) + (nB.z + nB.w);
            d0 = row_sum16(d0); n0 = row_sum16(n0);
            d1 = row_sum16(d1); n1 = row_sum16(n1);

            float s0 = d0 * beA / (knA * sqrtf(n0) + EPS_F);
            float s1 = d1 * beB / (knB * sqrtf(n1) + EPS_F);
            if (wsl == c) {               // 4 lanes (hp=0..3) write 8 heads
                s_sc[hp][cell]     = s0;
                s_sc[hp + 4][cell] = s1;
            }
        }

        // ---- epilogue behind raw barrier (keeps prefetch in flight) ----
        asm volatile("s_waitcnt lgkmcnt(0)" ::: "memory");
        __builtin_amdgcn_s_barrier();
        __builtin_amdgcn_sched_barrier(0);
        if (t < 128) {                    // 16-lane group per (head, tile)
            const int oh = t >> 4, oc = t & 15;
            float sc = s_sc[oh][oc];
            out[((size_t)(b * H + oh)) * CELLS + c0 + nt * TC + oc] = sc;
            float mx = sc;
#pragma unroll
            for (int s = 1; s <= 8; s <<= 1) mx = fmaxf(mx, __shfl_xor(mx, s, 64));
            float e = expf(sc - mx);
#pragma unroll
            for (int s = 1; s <= 8; s <<= 1) e += __shfl_xor(e, s, 64);
            if (oc == 0)
                part[((size_t)(b * H + oh)) * NBLK + grp * NT + nt] =
                    make_float2(mx, e);
        }
        __builtin_amdgcn_sched_barrier(0);
    }
}

// ---------------------------------------------------------------------------
// Kernel B: combine 512 partials per row (butterfly) + normalize.
// grid = 512 (8 per row), 256 threads, 1 float4 per thread.
// ---------------------------------------------------------------------------
__global__ __launch_bounds__(256) void ca_norm(
    float* __restrict__ out, const float2* __restrict__ part)
{
    const int row = blockIdx.x >> 3;     // b*H + h
    const int seg = blockIdx.x & 7;
    const int t = threadIdx.x, lane = t & 63;

    const float2* __restrict__ pp = part + (size_t)row * NBLK;
    float2 a[8];
#pragma unroll
    for (int i = 0; i < 8; ++i) a[i] = pp[lane + i * 64];
    float gm = -INFINITY;
#pragma unroll
    for (int i = 0; i < 8; ++i) gm = fmaxf(gm, a[i].x);
#pragma unroll
    for (int s = 32; s; s >>= 1) gm = fmaxf(gm, __shfl_xor(gm, s, 64));
    float gs = 0.f;
#pragma unroll
    for (int i = 0; i < 8; ++i) gs += a[i].y * expf(a[i].x - gm);
#pragma unroll
    for (int s = 32; s; s >>= 1) gs += __shfl_xor(gs, s, 64);
    float inv = 1.0f / gs;

    float4* p = (float4*)(out + (size_t)row * CELLS) + seg * 256;
    float4 vv = p[t];
    vv.x = expf(vv.x - gm) * inv;
    vv.y = expf(vv.y - gm) * inv;
    vv.z = expf(vv.z - gm) * inv;
    vv.w = expf(vv.w - gm) * inv;
    p[t] = vv;
}

// ---------------------------------------------------------------------------
extern "C" void kernel_launch(void* const* d_in, const int* in_sizes, int n_in,
                              void* d_out, int out_size, void* d_ws, size_t ws_size,
                              hipStream_t stream) {
    (void)in_sizes; (void)n_in; (void)out_size; (void)ws_size;
    const float* memory = (const float*)d_in[0];
    const float* keys   = (const float*)d_in[1];
    const float* betas  = (const float*)d_in[2];
    const float* mask   = (const float*)d_in[3];
    float* out = (float*)d_out;
    float2* part = (float2*)d_ws;

    dim3 gA(GX, B);
    ca_scores<<<gA, 256, 0, stream>>>((const float4*)memory,
                                      (const float4*)keys, (const float4*)mask,
                                      betas, out, part);
    ca_norm<<<8 * B * H, 256, 0, stream>>>(out, part);
}

// Round 9
// 29.209 us; speedup vs baseline: 1.1280x; 1.1280x over previous
//
#include <hip/hip_runtime.h>
#include <cstdint>
#include <cmath>

#define EPS_F 1e-8f

constexpr int B = 8, H = 8, CELLS = 8192, W = 256;
constexpr int W4 = 64;             // float4 per W-row
constexpr int CPW = 16;            // cells per wave
constexpr int CPB = 64;            // cells per block (4 waves)
constexpr int NBLK = CELLS / CPB;  // 128 blocks per (b) row

// ---- DPP rotate-add reduction over a row of 16 lanes (pure VALU) ----------
template <int CTRL>
__device__ __forceinline__ float ror_add(float v) {
    int x = __builtin_amdgcn_update_dpp(0, __builtin_bit_cast(int, v),
                                        CTRL, 0xf, 0xf, false);
    return v + __builtin_bit_cast(float, x);
}
__device__ __forceinline__ float row_sum16(float v) {
    v = ror_add<0x121>(v);   // row_ror:1
    v = ror_add<0x122>(v);   // row_ror:2
    v = ror_add<0x124>(v);   // row_ror:4
    v = ror_add<0x128>(v);   // row_ror:8
    return v;                // every lane holds the 16-lane sum
}

// ---------------------------------------------------------------------------
// Kernel A: fused prep + scores + softmax partials. NO LDS data path.
// grid = (NBLK, B) = (128, 8), 256 threads (4 waves), 3 blocks/CU.
// lane = hp*16 + wsl; lane covers heads hp and hp+4 on W-slots
// {wsl, wsl+16, wsl+32, wsl+48}. kq/m2 table in 16 f4 VGPRs (built once).
// Each wave streams its 16 cell rows straight from global (16-distinct-f4
// broadcast window = 2 lines/instr), 3-cell-deep register prefetch,
// DPP row-reduction; scores transposed through a 2 KB LDS buffer.
// ---------------------------------------------------------------------------
__global__ __launch_bounds__(256, 3) void ca_scores(
    const float4* __restrict__ mem4,    // [B*CELLS][W4]
    const float4* __restrict__ keys4,   // [B*H][W4]
    const float4* __restrict__ mask4,   // [B*H][W4]
    const float* __restrict__ betas,    // [B*H]
    float* __restrict__ out,            // [B*H][CELLS]
    float2* __restrict__ part)          // [B*H][NBLK] (max, sumexp)
{
    __shared__ float s_sc[H][CPB + 1];   // score transpose buffer

    const int b = blockIdx.y, blk = blockIdx.x, t = threadIdx.x;
    const int lane = t & 63, wv = t >> 6;
    const int hp  = (lane >> 4) & 3;     // head-pair id (0..3)
    const int wsl = lane & 15;           // W-slot within quarter
    const int c0  = blk * CPB;
    const int cw0 = c0 + wv * CPW;       // this wave's first cell

    // ---- prep loads (L2-hot, oldest in vmcnt FIFO) ----
    const float4* __restrict__ kA = keys4 + (size_t)(b * 8 + hp) * W4;
    const float4* __restrict__ mA = mask4 + (size_t)(b * 8 + hp) * W4;
    const float4* __restrict__ kB = keys4 + (size_t)(b * 8 + hp + 4) * W4;
    const float4* __restrict__ mB = mask4 + (size_t)(b * 8 + hp + 4) * W4;
    float4 ka[4], ma[4], kb[4], mb[4];
#pragma unroll
    for (int j = 0; j < 4; ++j) {
        ka[j] = kA[j * 16 + wsl];  ma[j] = mA[j * 16 + wsl];
        kb[j] = kB[j * 16 + wsl];  mb[j] = mB[j * 16 + wsl];
    }
    const float beA = betas[b * 8 + hp];
    const float beB = betas[b * 8 + hp + 4];

    // ---- issue first 2 cells' loads (overlap with table build) ----
    const float4* __restrict__ gro =
        mem4 + ((size_t)b * CELLS + cw0) * W4 + wsl;
    float4 pf[3][4];
#define LOADC(slot, i)                                                       \
    { const float4* __restrict__ p = gro + (i) * W4;                         \
      pf[slot][0] = p[0];  pf[slot][1] = p[16];                              \
      pf[slot][2] = p[32]; pf[slot][3] = p[48]; }
    LOADC(0, 0)
    LOADC(1, 1)

    // ---- build per-lane kq/m2 table + keys_norm (MASK_MIN = 0) ----
    float4 tb[16];
    float pA = 0.f, pB = 0.f;
#pragma unroll
    for (int j = 0; j < 4; ++j) {
        float4 m = ma[j], k = ka[j];
        float4 q = make_float4(m.x * m.x, m.y * m.y, m.z * m.z, m.w * m.w);
        tb[j * 4 + 0] = make_float4(k.x * q.x, k.y * q.y, k.z * q.z, k.w * q.w);
        tb[j * 4 + 1] = q;
        float km;
        km = k.x * m.x; pA = fmaf(km, km, pA);
        km = k.y * m.y; pA = fmaf(km, km, pA);
        km = k.z * m.z; pA = fmaf(km, km, pA);
        km = k.w * m.w; pA = fmaf(km, km, pA);
        m = mb[j]; k = kb[j];
        q = make_float4(m.x * m.x, m.y * m.y, m.z * m.z, m.w * m.w);
        tb[j * 4 + 2] = make_float4(k.x * q.x, k.y * q.y, k.z * q.z, k.w * q.w);
        tb[j * 4 + 3] = q;
        km = k.x * m.x; pB = fmaf(km, km, pB);
        km = k.y * m.y; pB = fmaf(km, km, pB);
        km = k.z * m.z; pB = fmaf(km, km, pB);
        km = k.w * m.w; pB = fmaf(km, km, pB);
    }
    const float knA = sqrtf(row_sum16(pA));
    const float knB = sqrtf(row_sum16(pB));

    // ---- main loop: 16 cells, 3-slot register rotation ----
#pragma unroll
    for (int i = 0; i < CPW; ++i) {
        if (i + 2 < CPW) LOADC((i + 2) % 3, i + 2)

        float4 dA = make_float4(0.f, 0.f, 0.f, 0.f);
        float4 nA = make_float4(0.f, 0.f, 0.f, 0.f);
        float4 dB = make_float4(0.f, 0.f, 0.f, 0.f);
        float4 nB = make_float4(0.f, 0.f, 0.f, 0.f);
#define ACC(a, j)                                                           \
        {                                                                   \
            float4 sq = make_float4(a.x * a.x, a.y * a.y, a.z * a.z, a.w * a.w); \
            float4 kqA = tb[(j) * 4 + 0], qA = tb[(j) * 4 + 1];             \
            float4 kqB = tb[(j) * 4 + 2], qB = tb[(j) * 4 + 3];             \
            dA.x = fmaf(a.x, kqA.x, dA.x); dA.y = fmaf(a.y, kqA.y, dA.y);   \
            dA.z = fmaf(a.z, kqA.z, dA.z); dA.w = fmaf(a.w, kqA.w, dA.w);   \
            nA.x = fmaf(sq.x, qA.x, nA.x); nA.y = fmaf(sq.y, qA.y, nA.y);   \
            nA.z = fmaf(sq.z, qA.z, nA.z); nA.w = fmaf(sq.w, qA.w, nA.w);   \
            dB.x = fmaf(a.x, kqB.x, dB.x); dB.y = fmaf(a.y, kqB.y, dB.y);   \
            dB.z = fmaf(a.z, kqB.z, dB.z); dB.w = fmaf(a.w, kqB.w, dB.w);   \
            nB.x = fmaf(sq.x, qB.x, nB.x); nB.y = fmaf(sq.y, qB.y, nB.y);   \
            nB.z = fmaf(sq.z, qB.z, nB.z); nB.w = fmaf(sq.w, qB.w, nB.w);   \
        }
        ACC(pf[i % 3][0], 0)
        ACC(pf[i % 3][1], 1)
        ACC(pf[i % 3][2], 2)
        ACC(pf[i % 3][3], 3)
#undef ACC

        float d0 = (dA.x + dA.y) + (dA.z + dA.w);
        float n0 = (nA.x + nA.y) + (nA.z + nA.w);
        float d1 = (dB.x + dB.y) + (dB.z + dB.w);
        float n1 = (nB.x + nB.y) + (nB.z + nB.w);
        d0 = row_sum16(d0); n0 = row_sum16(n0);
        d1 = row_sum16(d1); n1 = row_sum16(n1);

        float s0 = d0 * beA / (knA * sqrtf(n0) + EPS_F);
        float s1 = d1 * beB / (knB * sqrtf(n1) + EPS_F);
        if (wsl == i) {                  // 4 lanes (hp=0..3) write 8 heads
            s_sc[hp][wv * CPW + i]     = s0;
            s_sc[hp + 4][wv * CPW + i] = s1;
        }
    }
#undef LOADC
    __syncthreads();

    // ---- epilogue: coalesced store + per-head block max/sumexp ----
    const int oh = t >> 5, oc = t & 31;   // 32-thread group per head
    float sc0 = s_sc[oh][oc];
    float sc1 = s_sc[oh][oc + 32];
    const size_t orow = ((size_t)(b * H + oh)) * CELLS + c0;
    out[orow + oc]      = sc0;
    out[orow + oc + 32] = sc1;

    float mx = fmaxf(sc0, sc1);
#pragma unroll
    for (int s = 1; s <= 16; s <<= 1) mx = fmaxf(mx, __shfl_xor(mx, s, 64));
    float e = expf(sc0 - mx) + expf(sc1 - mx);
#pragma unroll
    for (int s = 1; s <= 16; s <<= 1) e += __shfl_xor(e, s, 64);
    if (oc == 0)
        part[((size_t)(b * H + oh)) * NBLK + blk] = make_float2(mx, e);
}

// ---------------------------------------------------------------------------
// Kernel B: combine 128 partials per row (butterfly) + normalize.
// grid = 512 (8 per row), 256 threads, 1 float4 per thread.
// ---------------------------------------------------------------------------
__global__ __launch_bounds__(256) void ca_norm(
    float* __restrict__ out, const float2* __restrict__ part)
{
    const int row = blockIdx.x >> 3;     // b*H + h
    const int seg = blockIdx.x & 7;
    const int t = threadIdx.x, lane = t & 63;

    const float2* __restrict__ pp = part + (size_t)row * NBLK;
    float2 a0 = pp[lane], a1 = pp[lane + 64];
    float gm = fmaxf(a0.x, a1.x);
#pragma unroll
    for (int s = 32; s; s >>= 1) gm = fmaxf(gm, __shfl_xor(gm, s, 64));
    float gs = a0.y * expf(a0.x - gm) + a1.y * expf(a1.x - gm);
#pragma unroll
    for (int s = 32; s; s >>= 1) gs += __shfl_xor(gs, s, 64);
    float inv = 1.0f / gs;

    float4* p = (float4*)(out + (size_t)row * CELLS) + seg * 256;
    float4 vv = p[t];
    vv.x = expf(vv.x - gm) * inv;
    vv.y = expf(vv.y - gm) * inv;
    vv.z = expf(vv.z - gm) * inv;
    vv.w = expf(vv.w - gm) * inv;
    p[t] = vv;
}

// ---------------------------------------------------------------------------
extern "C" void kernel_launch(void* const* d_in, const int* in_sizes, int n_in,
                              void* d_out, int out_size, void* d_ws, size_t ws_size,
                              hipStream_t stream) {
    (void)in_sizes; (void)n_in; (void)out_size; (void)ws_size;
    const float* memory = (const float*)d_in[0];
    const float* keys   = (const float*)d_in[1];
    const float* betas  = (const float*)d_in[2];
    const float* mask   = (const float*)d_in[3];
    float* out = (float*)d_out;
    float2* part = (float2*)d_ws;

    dim3 gA(NBLK, B);
    ca_scores<<<gA, 256, 0, stream>>>((const float4*)memory,
                                      (const float4*)keys, (const float4*)mask,
                                      betas, out, part);
    ca_norm<<<8 * B * H, 256, 0, stream>>>(out, part);
}